// Round 26
// baseline (120.642 us; speedup 1.0000x reference)
//
#include <hip/hip_runtime.h>
#include <hip/hip_bf16.h>

typedef unsigned short u16;
typedef unsigned int u32;
typedef __attribute__((ext_vector_type(8))) __bf16 bf16x8;
typedef __attribute__((ext_vector_type(4))) float f32x4;
typedef __attribute__((ext_vector_type(16))) float f32x16;
typedef __attribute__((ext_vector_type(2))) unsigned u32x2;
typedef __attribute__((ext_vector_type(4))) unsigned short u16x4;

// f32 -> bf16 round-to-nearest-even
__device__ __forceinline__ u16 f2bf(float f) {
  u32 u = __builtin_bit_cast(u32, f);
  return (u16)((u + 0x7fffu + ((u >> 16) & 1u)) >> 16);
}
__device__ __forceinline__ float bf2f(u16 h) {
  u32 u = ((u32)h) << 16;
  return __builtin_bit_cast(float, u);
}
__device__ __forceinline__ u32 pk2(float lo, float hi) {
  union { __bf16 b[2]; u32 u; } r;
  r.b[0] = (__bf16)lo; r.b[1] = (__bf16)hi;
  return r.u;
}

// permlane32_swap intrinsic wrapper (round-5 post-mortem: never raw asm with
// "+v","+v" on same-value operands — allocator may merge them).
__device__ __forceinline__ void pl32pair(u32& a, u32& b) {
#if __has_builtin(__builtin_amdgcn_permlane32_swap)
  u32x2 r = __builtin_amdgcn_permlane32_swap(a, b, 0, 0);
  a = r.x; b = r.y;
#else
  int hi = (int)((threadIdx.x & 63) >> 5);
  u32 as = __shfl_xor(a, 32), bs = __shfl_xor(b, 32);
  u32 na = hi ? bs : a;
  u32 nb = hi ? b : as;
  a = na; b = nb;
#endif
}
__device__ __forceinline__ float red_max32(float x) {
  u32 a = __builtin_bit_cast(u32, x), b = __builtin_bit_cast(u32, x);
  pl32pair(a, b);
  return fmaxf(__builtin_bit_cast(float, a), __builtin_bit_cast(float, b));
}
__device__ __forceinline__ float red_sum32(float x) {
  u32 a = __builtin_bit_cast(u32, x), b = __builtin_bit_cast(u32, x);
  pl32pair(a, b);
  return __builtin_bit_cast(float, a) + __builtin_bit_cast(float, b);
}

// ---------- cast + transpose W: [2048][256] f32 -> Wbt[768][2048] bf16 ----------
__global__ void cast_w_kernel(const float* __restrict__ Wq, const float* __restrict__ Wk,
                              const float* __restrict__ Wv, u16* __restrict__ wbt) {
  __shared__ float tile[32][33];
  int e0 = blockIdx.x * 32, d0 = blockIdx.y * 32, w = blockIdx.z;
  const float* W = (w == 0) ? Wq : ((w == 1) ? Wk : Wv);
  int x = threadIdx.x, y = threadIdx.y;
#pragma unroll
  for (int j = 0; j < 4; j++)
    tile[y + j * 8][x] = W[(size_t)(e0 + y + j * 8) * 256 + d0 + x];
  __syncthreads();
#pragma unroll
  for (int j = 0; j < 4; j++)
    wbt[(size_t)(w * 256 + d0 + y + j * 8) * 2048 + e0 + x] = f2bf(tile[x][y + j * 8]);
}

// ------- GEMM v5 (session best): cast_x fused into A staging + fused epilogue -------
__global__ __launch_bounds__(256, 2) void gemm_kernel(const float* __restrict__ X,
                                                      const u16* __restrict__ Bt,
                                                      u16* __restrict__ qbuf,
                                                      u16* __restrict__ kfrag,
                                                      u16* __restrict__ vfrag) {
  __shared__ __align__(16) u16 As[3][4096];  // 128 rows x 32 cols
  __shared__ __align__(16) u16 Bs[3][6144];  // 192 rows x 32 cols

  int tid = threadIdx.x;
  int w = tid >> 6, l = tid & 63;
  int lr = l & 15, lg = l >> 4;
  int wm = w >> 1, wn = w & 1;

  int bid = blockIdx.x;
  int xcd = bid & 7;
  int idx = bid >> 3;
  int rowb = xcd * 16 + (idx >> 2);   // A panel read once per XCD
  int colb = idx & 3;
  int row0 = rowb * 128, col0 = colb * 192;

  int arow = w * 16 + (l >> 2);
  int achunk = l & 3;
  int aswz = achunk ^ ((l >> 3) & 3);
  const float* gax = X + (size_t)(row0 + arow) * 2048 + achunk * 8;
  float4 areg[2][2];

  int garow = w * 16 + (l >> 2);
  int scol = ((l & 3) * 8) ^ (((l >> 3) & 3) * 8);
  const u16* gb = Bt + (size_t)(col0 + garow) * 2048 + scol;

  f32x4 acc[4][6];
#pragma unroll
  for (int m = 0; m < 4; m++)
#pragma unroll
    for (int n = 0; n < 6; n++) acc[m][n] = (f32x4){0.f, 0.f, 0.f, 0.f};

  int rcol = (lg * 8) ^ (((lr >> 1) & 3) * 8);

#define LOAD_A(ts)                                                        \
  {                                                                       \
    _Pragma("unroll") for (int c = 0; c < 2; c++) {                       \
      const float* p = gax + (size_t)c * 64 * 2048 + (ts) * 32;           \
      areg[c][0] = *(const float4*)p;                                     \
      areg[c][1] = *(const float4*)(p + 4);                               \
    }                                                                     \
  }
#define WRITE_A(bi_)                                                      \
  {                                                                       \
    _Pragma("unroll") for (int c = 0; c < 2; c++) {                       \
      union { u16 h[8]; uint4 v; } oa;                                    \
      oa.h[0] = f2bf(areg[c][0].x); oa.h[1] = f2bf(areg[c][0].y);         \
      oa.h[2] = f2bf(areg[c][0].z); oa.h[3] = f2bf(areg[c][0].w);         \
      oa.h[4] = f2bf(areg[c][1].x); oa.h[5] = f2bf(areg[c][1].y);         \
      oa.h[6] = f2bf(areg[c][1].z); oa.h[7] = f2bf(areg[c][1].w);         \
      *(uint4*)&As[bi_][(c * 64 + arow) * 32 + aswz * 8] = oa.v;          \
    }                                                                     \
  }
#define STAGE_B3(ts, bi_)                                                 \
  {                                                                       \
    _Pragma("unroll") for (int c = 0; c < 3; c++)                         \
        __builtin_amdgcn_global_load_lds(                                 \
            (const __attribute__((address_space(1))) void*)(gb + (size_t)c * 64 * 2048 + (ts) * 32), \
            (__attribute__((address_space(3))) void*)&Bs[bi_][(c * 64 + w * 16) * 32], 16, 0, 0); \
  }

  LOAD_A(0);
  WRITE_A(0);
  LOAD_A(1);
  STAGE_B3(0, 0);
  STAGE_B3(1, 1);
  asm volatile("s_waitcnt vmcnt(3)" ::: "memory");
  asm volatile("s_waitcnt lgkmcnt(0)" ::: "memory");
  __builtin_amdgcn_s_barrier();

  int bi = 0, bn = 1, bp = 2;
  for (int t = 0; t < 64; t++) {
    int ts = (t + 2 <= 63) ? (t + 2) : 63;
    const u16* asb = As[bi];
    const u16* bsb = Bs[bi];

    bf16x8 bfr[6], af0, af1;
#pragma unroll
    for (int n = 0; n < 6; n++)
      bfr[n] = *(const bf16x8*)&bsb[(wn * 96 + n * 16 + lr) * 32 + rcol];
    af0 = *(const bf16x8*)&asb[(wm * 64 + 0 * 16 + lr) * 32 + rcol];
    af1 = *(const bf16x8*)&asb[(wm * 64 + 1 * 16 + lr) * 32 + rcol];
    WRITE_A(bn);
    LOAD_A(ts);
    __builtin_amdgcn_s_barrier();
    asm volatile("s_waitcnt lgkmcnt(0)" ::: "memory");
    __builtin_amdgcn_sched_barrier(0);
    __builtin_amdgcn_s_setprio(1);
#pragma unroll
    for (int n = 0; n < 6; n++) {
      acc[0][n] = __builtin_amdgcn_mfma_f32_16x16x32_bf16(af0, bfr[n], acc[0][n], 0, 0, 0);
      acc[1][n] = __builtin_amdgcn_mfma_f32_16x16x32_bf16(af1, bfr[n], acc[1][n], 0, 0, 0);
    }
    __builtin_amdgcn_s_setprio(0);
    __builtin_amdgcn_s_barrier();

    bf16x8 af2, af3;
    af2 = *(const bf16x8*)&asb[(wm * 64 + 2 * 16 + lr) * 32 + rcol];
    af3 = *(const bf16x8*)&asb[(wm * 64 + 3 * 16 + lr) * 32 + rcol];
    STAGE_B3(ts, bp);
    __builtin_amdgcn_s_barrier();
    asm volatile("s_waitcnt lgkmcnt(0)" ::: "memory");
    __builtin_amdgcn_sched_barrier(0);
    __builtin_amdgcn_s_setprio(1);
#pragma unroll
    for (int n = 0; n < 6; n++) {
      acc[2][n] = __builtin_amdgcn_mfma_f32_16x16x32_bf16(af2, bfr[n], acc[2][n], 0, 0, 0);
      acc[3][n] = __builtin_amdgcn_mfma_f32_16x16x32_bf16(af3, bfr[n], acc[3][n], 0, 0, 0);
    }
    __builtin_amdgcn_s_setprio(0);
    asm volatile("s_waitcnt vmcnt(7)" ::: "memory");
    __builtin_amdgcn_s_barrier();

    bi = (bi == 2) ? 0 : bi + 1;
    bn = (bn == 2) ? 0 : bn + 1;
    bp = (bp == 2) ? 0 : bp + 1;
  }
#undef LOAD_A
#undef WRITE_A
#undef STAGE_B3

  int crow = row0 + wm * 64;
#pragma unroll
  for (int m = 0; m < 4; m++) {
    int t0 = crow + m * 16 + lg * 4;
    int bb = t0 >> 11, tm0 = t0 & 2047;
#pragma unroll
    for (int n = 0; n < 6; n++) {
      int cb = col0 + wn * 96 + n * 16;
      int c = cb + lr;
      if (cb < 256) {
#pragma unroll
        for (int i = 0; i < 4; i++)
          qbuf[(size_t)(t0 + i) * 256 + c] = f2bf(acc[m][n][i]);
      } else if (cb < 512) {
        int kc = c - 256;
        int kvb = tm0 >> 5;
        int t16 = kc >> 4;
        int lhalf = (kc >> 3) & 1;
        int jj = kc & 7;
        size_t base = ((size_t)((bb * 64 + kvb) * 16 + t16) * 64 + lhalf * 32) * 8 + jj;
#pragma unroll
        for (int i = 0; i < 4; i++)
          kfrag[base + (size_t)((tm0 + i) & 31) * 8] = f2bf(acc[m][n][i]);
      } else {
        int vc = c - 512;
        int kvb = tm0 >> 5;
        int ch = (tm0 >> 4) & 1;
        int lhalf = (tm0 >> 3) & 1;
        int jj = tm0 & 7;
        int dblk = vc >> 5;
        int lane = (vc & 31) + lhalf * 32;
        size_t base = ((size_t)(((bb * 64 + kvb) * 2 + ch) * 8 + dblk) * 64 + lane) * 8 + jj;
        u16x4 pk = {f2bf(acc[m][n][0]), f2bf(acc[m][n][1]),
                    f2bf(acc[m][n][2]), f2bf(acc[m][n][3])};
        *(u16x4*)(vfrag + base) = pk;
      }
    }
  }
}

// -------- flash attention v11 (session best): qlds + double-buffered klds --------
__global__ __launch_bounds__(512, 2) void attn_kernel(const u16* __restrict__ qbuf,
                                                      const u16* __restrict__ kfrag,
                                                      const u16* __restrict__ vfrag,
                                                      float* __restrict__ out) {
  __shared__ __align__(16) u16 qlds[16 * 512];          // 16 KB
  __shared__ __align__(16) u16 klds2[2][4 * 16 * 512];  // 128 KB
  __shared__ float sm[4][32];
  __shared__ float sl[4][32];
  float (*facc)[264] = (float (*)[264]) & klds2[0][0];  // merge-time alias

  int tid = threadIdx.x;
  int w = tid >> 6, l = tid & 63;
  int ql = l & 31, hi = l >> 5;
  int stream = w & 3, dhalf = w >> 2;
  int bid = blockIdx.x;
  int b = bid & 7;
  int p = bid >> 3;

#define STAGE_K(jb_, buf_)                                                           \
  {                                                                                  \
    _Pragma("unroll") for (int t = 0; t < 16; t++)                                   \
        __builtin_amdgcn_global_load_lds(                                            \
            (const __attribute__((address_space(1))) void*)(                         \
                kfrag + ((size_t)((b * 64 + (jb_)) * 16 + t) * 64 + l) * 8),         \
            (__attribute__((address_space(3))) void*)&klds2[buf_][(stream * 16 + t) * 512], \
            16, 0, 0);                                                               \
  }

  for (int tile = 0; tile < 2; tile++) {
    int jt = tile ? p : (63 - p);
    int q0 = jt * 32;

    if (tile) __syncthreads();
#pragma unroll
    for (int c = 0; c < 2; c++) {
      int m = c * 512 + tid;
      int t16 = m >> 6, ll = m & 63;
      const u16* src = qbuf + (size_t)(b * 2048 + q0 + (ll & 31)) * 256 + t16 * 16 + (ll >> 5) * 8;
      union { u16 h[8]; bf16x8 v; } in, ov;
      in.v = *(const bf16x8*)src;
#pragma unroll
      for (int j = 0; j < 8; j++) ov.h[j] = f2bf(bf2f(in.h[j]) * (1.0f / 256.0f));
      *(bf16x8*)&qlds[(t16 * 64 + ll) * 8] = ov.v;
    }
    __syncthreads();

    f32x16 o[4];
#pragma unroll
    for (int d = 0; d < 4; d++)
#pragma unroll
      for (int r = 0; r < 16; r++) o[d][r] = 0.f;
    float mreg = -__builtin_inff(), ell = 0.f;

    int nround = (jt >> 2) + 1;

    if (w < 4 && stream <= jt) STAGE_K(stream, 0);

    for (int rr = 0; rr < nround; rr++) {
      int cur = rr & 1;
      int jb = rr * 4 + stream;

      if (w < 4) asm volatile("s_waitcnt vmcnt(0)" ::: "memory");
      __syncthreads();

      int jbn = jb + 4;
      if (w < 4 && rr + 1 < nround && jbn <= jt) STAGE_K(jbn, cur ^ 1);

      if (jb <= jt) {
        const u16* vb = vfrag + ((size_t)(b * 64 + jb) * 16 * 64 + l) * 8;
        bf16x8 ve0[4], ve1[4];
#pragma unroll
        for (int dd = 0; dd < 4; dd++) {
          ve0[dd] = *(const bf16x8*)(vb + (dhalf * 4 + dd) * 512);
          ve1[dd] = *(const bf16x8*)(vb + (8 + dhalf * 4 + dd) * 512);
        }

        const u16* kl = &klds2[cur][(stream * 16 * 64 + l) * 8];
        f32x16 sA, sB;
#pragma unroll
        for (int r = 0; r < 16; r++) { sA[r] = 0.f; sB[r] = 0.f; }
#pragma unroll
        for (int g = 0; g < 4; g++) {
          bf16x8 k0 = *(const bf16x8*)(kl + (g * 4 + 0) * 512);
          bf16x8 k1 = *(const bf16x8*)(kl + (g * 4 + 1) * 512);
          bf16x8 k2 = *(const bf16x8*)(kl + (g * 4 + 2) * 512);
          bf16x8 k3 = *(const bf16x8*)(kl + (g * 4 + 3) * 512);
          bf16x8 q0f = *(const bf16x8*)&qlds[((g * 4 + 0) * 64 + l) * 8];
          bf16x8 q1f = *(const bf16x8*)&qlds[((g * 4 + 1) * 64 + l) * 8];
          bf16x8 q2f = *(const bf16x8*)&qlds[((g * 4 + 2) * 64 + l) * 8];
          bf16x8 q3f = *(const bf16x8*)&qlds[((g * 4 + 3) * 64 + l) * 8];
          sA = __builtin_amdgcn_mfma_f32_32x32x16_bf16(k0, q0f, sA, 0, 0, 0);
          sB = __builtin_amdgcn_mfma_f32_32x32x16_bf16(k1, q1f, sB, 0, 0, 0);
          sA = __builtin_amdgcn_mfma_f32_32x32x16_bf16(k2, q2f, sA, 0, 0, 0);
          sB = __builtin_amdgcn_mfma_f32_32x32x16_bf16(k3, q3f, sB, 0, 0, 0);
        }

        float s[16];
#pragma unroll
        for (int r = 0; r < 16; r++) s[r] = sA[r] + sB[r];

        if (jb == jt) {
#pragma unroll
          for (int r = 0; r < 16; r++) {
            int kv = (r & 3) + 8 * (r >> 2) + 4 * hi;
            if (kv > ql) s[r] = -__builtin_inff();
          }
        }

        float mx = s[0];
#pragma unroll
        for (int r = 1; r < 16; r++) mx = fmaxf(mx, s[r]);
        mx = red_max32(mx);
        if (__any(mx > mreg + 8.f)) {
          float mnew = fmaxf(mreg, mx);
          float sf = __expf(mreg - mnew);
          mreg = mnew;
          ell *= sf;
#pragma unroll
          for (int d = 0; d < 4; d++)
#pragma unroll
            for (int r = 0; r < 16; r++) o[d][r] *= sf;
        }
        float pr[16], ps = 0.f;
#pragma unroll
        for (int r = 0; r < 16; r++) { pr[r] = __expf(s[r] - mreg); ps += pr[r]; }
        ell += red_sum32(ps);

        u32 wv[8];
#pragma unroll
        for (int i = 0; i < 8; i++) wv[i] = pk2(pr[2 * i], pr[2 * i + 1]);
        pl32pair(wv[0], wv[2]); pl32pair(wv[1], wv[3]);
        pl32pair(wv[4], wv[6]); pl32pair(wv[5], wv[7]);
        union { u32 u[4]; bf16x8 v; } B0, B1;
        B0.u[0] = wv[0]; B0.u[1] = wv[1]; B0.u[2] = wv[2]; B0.u[3] = wv[3];
        B1.u[0] = wv[4]; B1.u[1] = wv[5]; B1.u[2] = wv[6]; B1.u[3] = wv[7];

#pragma unroll
        for (int dd = 0; dd < 4; dd++) {
          o[dd] = __builtin_amdgcn_mfma_f32_32x32x16_bf16(ve0[dd], B0.v, o[dd], 0, 0, 0);
          o[dd] = __builtin_amdgcn_mfma_f32_32x32x16_bf16(ve1[dd], B1.v, o[dd], 0, 0, 0);
        }
      }
    }

    if (w < 4 && l < 32) { sm[w][l] = mreg; sl[w][l] = ell; }
    __syncthreads();

    float M = fmaxf(fmaxf(sm[0][ql], sm[1][ql]), fmaxf(sm[2][ql], sm[3][ql]));
    float alpha = __expf(mreg - M);

#pragma unroll
    for (int ph = 0; ph < 4; ph++) {
      if (stream == ph) {
#pragma unroll
        for (int dd = 0; dd < 4; dd++)
#pragma unroll
          for (int rq = 0; rq < 4; rq++) {
            int base = (dhalf * 4 + dd) * 32 + 8 * rq + 4 * hi;
            f32x4 v;
#pragma unroll
            for (int i = 0; i < 4; i++) v[i] = alpha * o[dd][rq * 4 + i];
            float* fp = &facc[ql][base];
            if (ph == 0) *(f32x4*)fp = v;
            else {
              f32x4 old = *(const f32x4*)fp;
              *(f32x4*)fp = old + v;
            }
          }
      }
      __syncthreads();
    }

    int r = tid >> 4, lt = tid & 15;
    float Mr = fmaxf(fmaxf(sm[0][r], sm[1][r]), fmaxf(sm[2][r], sm[3][r]));
    float denom = 0.f;
#pragma unroll
    for (int ww = 0; ww < 4; ww++) denom += __expf(sm[ww][r] - Mr) * sl[ww][r];
    float inv = 1.0f / denom;
    float* orow = out + (size_t)(b * 2048 + q0 + r) * 256;
#pragma unroll
    for (int j = 0; j < 4; j++) {
      int c = (lt + j * 16) * 4;
      f32x4 v = *(const f32x4*)&facc[r][c];
      v[0] *= inv; v[1] *= inv; v[2] *= inv; v[3] *= inv;
      *(f32x4*)&orow[c] = v;
    }
  }
#undef STAGE_K
}

extern "C" void kernel_launch(void* const* d_in, const int* in_sizes, int n_in,
                              void* d_out, int out_size, void* d_ws, size_t ws_size,
                              hipStream_t stream) {
  (void)in_sizes; (void)n_in; (void)out_size; (void)ws_size;
  const float* x = (const float*)d_in[0];
  const float* Wq = (const float*)d_in[1];
  const float* Wk = (const float*)d_in[2];
  const float* Wv = (const float*)d_in[3];
  float* out = (float*)d_out;

  char* ws = (char*)d_ws;
  u16* wbt   = (u16*)(ws + 67108864);       // [67,108,864, 70,254,592)
  u16* qbuf  = (u16*)(ws + 70254592);       // 16384*256*2 = 8,388,608
  u16* kfrag = (u16*)(ws + 78643200);       // 8,388,608
  u16* vfrag = (u16*)(ws + 87031808);       // 8,388,608  (ends 95,420,416)

  cast_w_kernel<<<dim3(64, 8, 3), dim3(32, 8), 0, stream>>>(Wq, Wk, Wv, wbt);
  gemm_kernel<<<512, 256, 0, stream>>>(x, wbt, qbuf, kfrag, vfrag);
  attn_kernel<<<256, 512, 0, stream>>>(qbuf, kfrag, vfrag, out);
}

// Round 27
// 120.438 us; speedup vs baseline: 1.0017x; 1.0017x over previous
//
#include <hip/hip_runtime.h>
#include <hip/hip_bf16.h>

typedef unsigned short u16;
typedef unsigned int u32;
typedef __attribute__((ext_vector_type(8))) __bf16 bf16x8;
typedef __attribute__((ext_vector_type(4))) float f32x4;
typedef __attribute__((ext_vector_type(16))) float f32x16;
typedef __attribute__((ext_vector_type(2))) unsigned u32x2;
typedef __attribute__((ext_vector_type(4))) unsigned short u16x4;

// f32 -> bf16 round-to-nearest-even
__device__ __forceinline__ u16 f2bf(float f) {
  u32 u = __builtin_bit_cast(u32, f);
  return (u16)((u + 0x7fffu + ((u >> 16) & 1u)) >> 16);
}
__device__ __forceinline__ float bf2f(u16 h) {
  u32 u = ((u32)h) << 16;
  return __builtin_bit_cast(float, u);
}
__device__ __forceinline__ u32 pk2(float lo, float hi) {
  union { __bf16 b[2]; u32 u; } r;
  r.b[0] = (__bf16)lo; r.b[1] = (__bf16)hi;
  return r.u;
}

// permlane32_swap intrinsic wrapper (round-5 post-mortem: never raw asm with
// "+v","+v" on same-value operands — allocator may merge them).
__device__ __forceinline__ void pl32pair(u32& a, u32& b) {
#if __has_builtin(__builtin_amdgcn_permlane32_swap)
  u32x2 r = __builtin_amdgcn_permlane32_swap(a, b, 0, 0);
  a = r.x; b = r.y;
#else
  int hi = (int)((threadIdx.x & 63) >> 5);
  u32 as = __shfl_xor(a, 32), bs = __shfl_xor(b, 32);
  u32 na = hi ? bs : a;
  u32 nb = hi ? b : as;
  a = na; b = nb;
#endif
}
__device__ __forceinline__ float red_max32(float x) {
  u32 a = __builtin_bit_cast(u32, x), b = __builtin_bit_cast(u32, x);
  pl32pair(a, b);
  return fmaxf(__builtin_bit_cast(float, a), __builtin_bit_cast(float, b));
}
__device__ __forceinline__ float red_sum32(float x) {
  u32 a = __builtin_bit_cast(u32, x), b = __builtin_bit_cast(u32, x);
  pl32pair(a, b);
  return __builtin_bit_cast(float, a) + __builtin_bit_cast(float, b);
}

// ---------- cast + transpose W: [2048][256] f32 -> Wbt[768][2048] bf16 ----------
__global__ void cast_w_kernel(const float* __restrict__ Wq, const float* __restrict__ Wk,
                              const float* __restrict__ Wv, u16* __restrict__ wbt) {
  __shared__ float tile[32][33];
  int e0 = blockIdx.x * 32, d0 = blockIdx.y * 32, w = blockIdx.z;
  const float* W = (w == 0) ? Wq : ((w == 1) ? Wk : Wv);
  int x = threadIdx.x, y = threadIdx.y;
#pragma unroll
  for (int j = 0; j < 4; j++)
    tile[y + j * 8][x] = W[(size_t)(e0 + y + j * 8) * 256 + d0 + x];
  __syncthreads();
#pragma unroll
  for (int j = 0; j < 4; j++)
    wbt[(size_t)(w * 256 + d0 + y + j * 8) * 2048 + e0 + x] = f2bf(tile[x][y + j * 8]);
}

// ------- GEMM v5 (session best): cast_x fused into A staging + fused epilogue -------
__global__ __launch_bounds__(256, 2) void gemm_kernel(const float* __restrict__ X,
                                                      const u16* __restrict__ Bt,
                                                      u16* __restrict__ qbuf,
                                                      u16* __restrict__ kfrag,
                                                      u16* __restrict__ vfrag) {
  __shared__ __align__(16) u16 As[3][4096];  // 128 rows x 32 cols
  __shared__ __align__(16) u16 Bs[3][6144];  // 192 rows x 32 cols

  int tid = threadIdx.x;
  int w = tid >> 6, l = tid & 63;
  int lr = l & 15, lg = l >> 4;
  int wm = w >> 1, wn = w & 1;

  int bid = blockIdx.x;
  int xcd = bid & 7;
  int idx = bid >> 3;
  int rowb = xcd * 16 + (idx >> 2);   // A panel read once per XCD
  int colb = idx & 3;
  int row0 = rowb * 128, col0 = colb * 192;

  int arow = w * 16 + (l >> 2);
  int achunk = l & 3;
  int aswz = achunk ^ ((l >> 3) & 3);
  const float* gax = X + (size_t)(row0 + arow) * 2048 + achunk * 8;
  float4 areg[2][2];

  int garow = w * 16 + (l >> 2);
  int scol = ((l & 3) * 8) ^ (((l >> 3) & 3) * 8);
  const u16* gb = Bt + (size_t)(col0 + garow) * 2048 + scol;

  f32x4 acc[4][6];
#pragma unroll
  for (int m = 0; m < 4; m++)
#pragma unroll
    for (int n = 0; n < 6; n++) acc[m][n] = (f32x4){0.f, 0.f, 0.f, 0.f};

  int rcol = (lg * 8) ^ (((lr >> 1) & 3) * 8);

#define LOAD_A(ts)                                                        \
  {                                                                       \
    _Pragma("unroll") for (int c = 0; c < 2; c++) {                       \
      const float* p = gax + (size_t)c * 64 * 2048 + (ts) * 32;           \
      areg[c][0] = *(const float4*)p;                                     \
      areg[c][1] = *(const float4*)(p + 4);                               \
    }                                                                     \
  }
#define WRITE_A(bi_)                                                      \
  {                                                                       \
    _Pragma("unroll") for (int c = 0; c < 2; c++) {                       \
      union { u16 h[8]; uint4 v; } oa;                                    \
      oa.h[0] = f2bf(areg[c][0].x); oa.h[1] = f2bf(areg[c][0].y);         \
      oa.h[2] = f2bf(areg[c][0].z); oa.h[3] = f2bf(areg[c][0].w);         \
      oa.h[4] = f2bf(areg[c][1].x); oa.h[5] = f2bf(areg[c][1].y);         \
      oa.h[6] = f2bf(areg[c][1].z); oa.h[7] = f2bf(areg[c][1].w);         \
      *(uint4*)&As[bi_][(c * 64 + arow) * 32 + aswz * 8] = oa.v;          \
    }                                                                     \
  }
#define STAGE_B3(ts, bi_)                                                 \
  {                                                                       \
    _Pragma("unroll") for (int c = 0; c < 3; c++)                         \
        __builtin_amdgcn_global_load_lds(                                 \
            (const __attribute__((address_space(1))) void*)(gb + (size_t)c * 64 * 2048 + (ts) * 32), \
            (__attribute__((address_space(3))) void*)&Bs[bi_][(c * 64 + w * 16) * 32], 16, 0, 0); \
  }

  LOAD_A(0);
  WRITE_A(0);
  LOAD_A(1);
  STAGE_B3(0, 0);
  STAGE_B3(1, 1);
  asm volatile("s_waitcnt vmcnt(3)" ::: "memory");
  asm volatile("s_waitcnt lgkmcnt(0)" ::: "memory");
  __builtin_amdgcn_s_barrier();

  int bi = 0, bn = 1, bp = 2;
  for (int t = 0; t < 64; t++) {
    int ts = (t + 2 <= 63) ? (t + 2) : 63;
    const u16* asb = As[bi];
    const u16* bsb = Bs[bi];

    bf16x8 bfr[6], af0, af1;
#pragma unroll
    for (int n = 0; n < 6; n++)
      bfr[n] = *(const bf16x8*)&bsb[(wn * 96 + n * 16 + lr) * 32 + rcol];
    af0 = *(const bf16x8*)&asb[(wm * 64 + 0 * 16 + lr) * 32 + rcol];
    af1 = *(const bf16x8*)&asb[(wm * 64 + 1 * 16 + lr) * 32 + rcol];
    WRITE_A(bn);
    LOAD_A(ts);
    __builtin_amdgcn_s_barrier();
    asm volatile("s_waitcnt lgkmcnt(0)" ::: "memory");
    __builtin_amdgcn_sched_barrier(0);
    __builtin_amdgcn_s_setprio(1);
#pragma unroll
    for (int n = 0; n < 6; n++) {
      acc[0][n] = __builtin_amdgcn_mfma_f32_16x16x32_bf16(af0, bfr[n], acc[0][n], 0, 0, 0);
      acc[1][n] = __builtin_amdgcn_mfma_f32_16x16x32_bf16(af1, bfr[n], acc[1][n], 0, 0, 0);
    }
    __builtin_amdgcn_s_setprio(0);
    __builtin_amdgcn_s_barrier();

    bf16x8 af2, af3;
    af2 = *(const bf16x8*)&asb[(wm * 64 + 2 * 16 + lr) * 32 + rcol];
    af3 = *(const bf16x8*)&asb[(wm * 64 + 3 * 16 + lr) * 32 + rcol];
    STAGE_B3(ts, bp);
    __builtin_amdgcn_s_barrier();
    asm volatile("s_waitcnt lgkmcnt(0)" ::: "memory");
    __builtin_amdgcn_sched_barrier(0);
    __builtin_amdgcn_s_setprio(1);
#pragma unroll
    for (int n = 0; n < 6; n++) {
      acc[2][n] = __builtin_amdgcn_mfma_f32_16x16x32_bf16(af2, bfr[n], acc[2][n], 0, 0, 0);
      acc[3][n] = __builtin_amdgcn_mfma_f32_16x16x32_bf16(af3, bfr[n], acc[3][n], 0, 0, 0);
    }
    __builtin_amdgcn_s_setprio(0);
    asm volatile("s_waitcnt vmcnt(7)" ::: "memory");
    __builtin_amdgcn_s_barrier();

    bi = (bi == 2) ? 0 : bi + 1;
    bn = (bn == 2) ? 0 : bn + 1;
    bp = (bp == 2) ? 0 : bp + 1;
  }
#undef LOAD_A
#undef WRITE_A
#undef STAGE_B3

  int crow = row0 + wm * 64;
#pragma unroll
  for (int m = 0; m < 4; m++) {
    int t0 = crow + m * 16 + lg * 4;
    int bb = t0 >> 11, tm0 = t0 & 2047;
#pragma unroll
    for (int n = 0; n < 6; n++) {
      int cb = col0 + wn * 96 + n * 16;
      int c = cb + lr;
      if (cb < 256) {
#pragma unroll
        for (int i = 0; i < 4; i++)
          qbuf[(size_t)(t0 + i) * 256 + c] = f2bf(acc[m][n][i]);
      } else if (cb < 512) {
        int kc = c - 256;
        int kvb = tm0 >> 5;
        int t16 = kc >> 4;
        int lhalf = (kc >> 3) & 1;
        int jj = kc & 7;
        size_t base = ((size_t)((bb * 64 + kvb) * 16 + t16) * 64 + lhalf * 32) * 8 + jj;
#pragma unroll
        for (int i = 0; i < 4; i++)
          kfrag[base + (size_t)((tm0 + i) & 31) * 8] = f2bf(acc[m][n][i]);
      } else {
        int vc = c - 512;
        int kvb = tm0 >> 5;
        int ch = (tm0 >> 4) & 1;
        int lhalf = (tm0 >> 3) & 1;
        int jj = tm0 & 7;
        int dblk = vc >> 5;
        int lane = (vc & 31) + lhalf * 32;
        size_t base = ((size_t)(((bb * 64 + kvb) * 2 + ch) * 8 + dblk) * 64 + lane) * 8 + jj;
        u16x4 pk = {f2bf(acc[m][n][0]), f2bf(acc[m][n][1]),
                    f2bf(acc[m][n][2]), f2bf(acc[m][n][3])};
        *(u16x4*)(vfrag + base) = pk;
      }
    }
  }
}

// -------- flash attention v11 (session best): qlds + double-buffered klds --------
__global__ __launch_bounds__(512, 2) void attn_kernel(const u16* __restrict__ qbuf,
                                                      const u16* __restrict__ kfrag,
                                                      const u16* __restrict__ vfrag,
                                                      float* __restrict__ out) {
  __shared__ __align__(16) u16 qlds[16 * 512];          // 16 KB
  __shared__ __align__(16) u16 klds2[2][4 * 16 * 512];  // 128 KB
  __shared__ float sm[4][32];
  __shared__ float sl[4][32];
  float (*facc)[264] = (float (*)[264]) & klds2[0][0];  // merge-time alias

  int tid = threadIdx.x;
  int w = tid >> 6, l = tid & 63;
  int ql = l & 31, hi = l >> 5;
  int stream = w & 3, dhalf = w >> 2;
  int bid = blockIdx.x;
  int b = bid & 7;
  int p = bid >> 3;

#define STAGE_K(jb_, buf_)                                                           \
  {                                                                                  \
    _Pragma("unroll") for (int t = 0; t < 16; t++)                                   \
        __builtin_amdgcn_global_load_lds(                                            \
            (const __attribute__((address_space(1))) void*)(                         \
                kfrag + ((size_t)((b * 64 + (jb_)) * 16 + t) * 64 + l) * 8),         \
            (__attribute__((address_space(3))) void*)&klds2[buf_][(stream * 16 + t) * 512], \
            16, 0, 0);                                                               \
  }

  for (int tile = 0; tile < 2; tile++) {
    int jt = tile ? p : (63 - p);
    int q0 = jt * 32;

    if (tile) __syncthreads();
#pragma unroll
    for (int c = 0; c < 2; c++) {
      int m = c * 512 + tid;
      int t16 = m >> 6, ll = m & 63;
      const u16* src = qbuf + (size_t)(b * 2048 + q0 + (ll & 31)) * 256 + t16 * 16 + (ll >> 5) * 8;
      union { u16 h[8]; bf16x8 v; } in, ov;
      in.v = *(const bf16x8*)src;
#pragma unroll
      for (int j = 0; j < 8; j++) ov.h[j] = f2bf(bf2f(in.h[j]) * (1.0f / 256.0f));
      *(bf16x8*)&qlds[(t16 * 64 + ll) * 8] = ov.v;
    }
    __syncthreads();

    f32x16 o[4];
#pragma unroll
    for (int d = 0; d < 4; d++)
#pragma unroll
      for (int r = 0; r < 16; r++) o[d][r] = 0.f;
    float mreg = -__builtin_inff(), ell = 0.f;

    int nround = (jt >> 2) + 1;

    if (w < 4 && stream <= jt) STAGE_K(stream, 0);

    for (int rr = 0; rr < nround; rr++) {
      int cur = rr & 1;
      int jb = rr * 4 + stream;

      if (w < 4) asm volatile("s_waitcnt vmcnt(0)" ::: "memory");
      __syncthreads();

      int jbn = jb + 4;
      if (w < 4 && rr + 1 < nround && jbn <= jt) STAGE_K(jbn, cur ^ 1);

      if (jb <= jt) {
        const u16* vb = vfrag + ((size_t)(b * 64 + jb) * 16 * 64 + l) * 8;
        bf16x8 ve0[4], ve1[4];
#pragma unroll
        for (int dd = 0; dd < 4; dd++) {
          ve0[dd] = *(const bf16x8*)(vb + (dhalf * 4 + dd) * 512);
          ve1[dd] = *(const bf16x8*)(vb + (8 + dhalf * 4 + dd) * 512);
        }

        const u16* kl = &klds2[cur][(stream * 16 * 64 + l) * 8];
        f32x16 sA, sB;
#pragma unroll
        for (int r = 0; r < 16; r++) { sA[r] = 0.f; sB[r] = 0.f; }
#pragma unroll
        for (int g = 0; g < 4; g++) {
          bf16x8 k0 = *(const bf16x8*)(kl + (g * 4 + 0) * 512);
          bf16x8 k1 = *(const bf16x8*)(kl + (g * 4 + 1) * 512);
          bf16x8 k2 = *(const bf16x8*)(kl + (g * 4 + 2) * 512);
          bf16x8 k3 = *(const bf16x8*)(kl + (g * 4 + 3) * 512);
          bf16x8 q0f = *(const bf16x8*)&qlds[((g * 4 + 0) * 64 + l) * 8];
          bf16x8 q1f = *(const bf16x8*)&qlds[((g * 4 + 1) * 64 + l) * 8];
          bf16x8 q2f = *(const bf16x8*)&qlds[((g * 4 + 2) * 64 + l) * 8];
          bf16x8 q3f = *(const bf16x8*)&qlds[((g * 4 + 3) * 64 + l) * 8];
          sA = __builtin_amdgcn_mfma_f32_32x32x16_bf16(k0, q0f, sA, 0, 0, 0);
          sB = __builtin_amdgcn_mfma_f32_32x32x16_bf16(k1, q1f, sB, 0, 0, 0);
          sA = __builtin_amdgcn_mfma_f32_32x32x16_bf16(k2, q2f, sA, 0, 0, 0);
          sB = __builtin_amdgcn_mfma_f32_32x32x16_bf16(k3, q3f, sB, 0, 0, 0);
        }

        float s[16];
#pragma unroll
        for (int r = 0; r < 16; r++) s[r] = sA[r] + sB[r];

        if (jb == jt) {
#pragma unroll
          for (int r = 0; r < 16; r++) {
            int kv = (r & 3) + 8 * (r >> 2) + 4 * hi;
            if (kv > ql) s[r] = -__builtin_inff();
          }
        }

        float mx = s[0];
#pragma unroll
        for (int r = 1; r < 16; r++) mx = fmaxf(mx, s[r]);
        mx = red_max32(mx);
        if (__any(mx > mreg + 8.f)) {
          float mnew = fmaxf(mreg, mx);
          float sf = __expf(mreg - mnew);
          mreg = mnew;
          ell *= sf;
#pragma unroll
          for (int d = 0; d < 4; d++)
#pragma unroll
            for (int r = 0; r < 16; r++) o[d][r] *= sf;
        }
        float pr[16], ps = 0.f;
#pragma unroll
        for (int r = 0; r < 16; r++) { pr[r] = __expf(s[r] - mreg); ps += pr[r]; }
        ell += red_sum32(ps);

        u32 wv[8];
#pragma unroll
        for (int i = 0; i < 8; i++) wv[i] = pk2(pr[2 * i], pr[2 * i + 1]);
        pl32pair(wv[0], wv[2]); pl32pair(wv[1], wv[3]);
        pl32pair(wv[4], wv[6]); pl32pair(wv[5], wv[7]);
        union { u32 u[4]; bf16x8 v; } B0, B1;
        B0.u[0] = wv[0]; B0.u[1] = wv[1]; B0.u[2] = wv[2]; B0.u[3] = wv[3];
        B1.u[0] = wv[4]; B1.u[1] = wv[5]; B1.u[2] = wv[6]; B1.u[3] = wv[7];

#pragma unroll
        for (int dd = 0; dd < 4; dd++) {
          o[dd] = __builtin_amdgcn_mfma_f32_32x32x16_bf16(ve0[dd], B0.v, o[dd], 0, 0, 0);
          o[dd] = __builtin_amdgcn_mfma_f32_32x32x16_bf16(ve1[dd], B1.v, o[dd], 0, 0, 0);
        }
      }
    }

    if (w < 4 && l < 32) { sm[w][l] = mreg; sl[w][l] = ell; }
    __syncthreads();

    float M = fmaxf(fmaxf(sm[0][ql], sm[1][ql]), fmaxf(sm[2][ql], sm[3][ql]));
    float alpha = __expf(mreg - M);

#pragma unroll
    for (int ph = 0; ph < 4; ph++) {
      if (stream == ph) {
#pragma unroll
        for (int dd = 0; dd < 4; dd++)
#pragma unroll
          for (int rq = 0; rq < 4; rq++) {
            int base = (dhalf * 4 + dd) * 32 + 8 * rq + 4 * hi;
            f32x4 v;
#pragma unroll
            for (int i = 0; i < 4; i++) v[i] = alpha * o[dd][rq * 4 + i];
            float* fp = &facc[ql][base];
            if (ph == 0) *(f32x4*)fp = v;
            else {
              f32x4 old = *(const f32x4*)fp;
              *(f32x4*)fp = old + v;
            }
          }
      }
      __syncthreads();
    }

    int r = tid >> 4, lt = tid & 15;
    float Mr = fmaxf(fmaxf(sm[0][r], sm[1][r]), fmaxf(sm[2][r], sm[3][r]));
    float denom = 0.f;
#pragma unroll
    for (int ww = 0; ww < 4; ww++) denom += __expf(sm[ww][r] - Mr) * sl[ww][r];
    float inv = 1.0f / denom;
    float* orow = out + (size_t)(b * 2048 + q0 + r) * 256;
#pragma unroll
    for (int j = 0; j < 4; j++) {
      int c = (lt + j * 16) * 4;
      f32x4 v = *(const f32x4*)&facc[r][c];
      v[0] *= inv; v[1] *= inv; v[2] *= inv; v[3] *= inv;
      *(f32x4*)&orow[c] = v;
    }
  }
#undef STAGE_K
}

extern "C" void kernel_launch(void* const* d_in, const int* in_sizes, int n_in,
                              void* d_out, int out_size, void* d_ws, size_t ws_size,
                              hipStream_t stream) {
  (void)in_sizes; (void)n_in; (void)out_size; (void)ws_size;
  const float* x = (const float*)d_in[0];
  const float* Wq = (const float*)d_in[1];
  const float* Wk = (const float*)d_in[2];
  const float* Wv = (const float*)d_in[3];
  float* out = (float*)d_out;

  char* ws = (char*)d_ws;
  u16* wbt   = (u16*)(ws + 67108864);       // [67,108,864, 70,254,592)
  u16* qbuf  = (u16*)(ws + 70254592);       // 16384*256*2 = 8,388,608
  u16* kfrag = (u16*)(ws + 78643200);       // 8,388,608
  u16* vfrag = (u16*)(ws + 87031808);       // 8,388,608  (ends 95,420,416)

  cast_w_kernel<<<dim3(64, 8, 3), dim3(32, 8), 0, stream>>>(Wq, Wk, Wv, wbt);
  gemm_kernel<<<512, 256, 0, stream>>>(x, wbt, qbuf, kfrag, vfrag);
  attn_kernel<<<256, 512, 0, stream>>>(qbuf, kfrag, vfrag, out);
}